// Round 1
// baseline (1905.492 us; speedup 1.0000x reference)
//
#include <hip/hip_runtime.h>
#include <stdint.h>

// ---------- types ----------
typedef short bf16x8   __attribute__((ext_vector_type(8)));
typedef short short4v  __attribute__((ext_vector_type(4)));
typedef short short8v  __attribute__((ext_vector_type(8)));
typedef float f32x4    __attribute__((ext_vector_type(4)));

typedef __attribute__((address_space(3))) uint32_t lds_u32;
typedef const __attribute__((address_space(1))) uint32_t glob_u32;

__device__ __forceinline__ void gl_lds16(const void* g, void* l) {
  __builtin_amdgcn_global_load_lds((glob_u32*)g, (lds_u32*)l, 16, 0, 0);
}

__device__ __forceinline__ float bf2f(short u) {
  union { float f; uint32_t i; } v; v.i = ((uint32_t)(uint16_t)u) << 16; return v.f;
}
__device__ __forceinline__ short f2bf(float f) {
  union { float f; uint32_t i; } v; v.f = f;
  uint32_t r = v.i + 0x7FFFu + ((v.i >> 16) & 1u);
  return (short)(r >> 16);
}
__device__ __forceinline__ float siluf(float x) {
  return x * __builtin_amdgcn_rcpf(1.0f + __expf(-x));
}
__device__ __forceinline__ f32x4 mfma16(bf16x8 a, bf16x8 b, f32x4 c) {
  return __builtin_amdgcn_mfma_f32_16x16x32_bf16(a, b, c, 0, 0, 0);
}

// ---------- K1: LayerNorm(x) -> bf16 ----------
// one wave per row of 512; 4 rows/block
__global__ __launch_bounds__(256) void k_ln(const float* __restrict__ x, short* __restrict__ xn) {
  int row = blockIdx.x * 4 + (threadIdx.x >> 6);
  int lane = threadIdx.x & 63;
  const float4* xr = (const float4*)(x + (size_t)row * 512);
  float4 a = xr[lane * 2], b = xr[lane * 2 + 1];
  float s  = a.x + a.y + a.z + a.w + b.x + b.y + b.z + b.w;
  float s2 = a.x*a.x + a.y*a.y + a.z*a.z + a.w*a.w + b.x*b.x + b.y*b.y + b.z*b.z + b.w*b.w;
#pragma unroll
  for (int m = 1; m < 64; m <<= 1) { s += __shfl_xor(s, m); s2 += __shfl_xor(s2, m); }
  float mu = s * (1.f / 512.f);
  float rstd = rsqrtf(s2 * (1.f / 512.f) - mu * mu + 1e-6f);
  float v[8] = {a.x, a.y, a.z, a.w, b.x, b.y, b.z, b.w};
  short8v o;
#pragma unroll
  for (int j = 0; j < 8; ++j) o[j] = f2bf((v[j] - mu) * rstd);
  *(short8v*)&xn[(size_t)row * 512 + lane * 8] = o;
}

// ---------- K2: transpose+cast uvqk (512x2048) -> Wt (2048x512) bf16 ----------
__global__ __launch_bounds__(256) void k_prep_w(const float* __restrict__ uvqk, short* __restrict__ Wt) {
  __shared__ float t[64][65];
  int k0 = blockIdx.x * 64;   // 8 tiles over K=512
  int c0 = blockIdx.y * 64;   // 32 tiles over C=2048
  for (int i = threadIdx.x; i < 64 * 64; i += 256) {
    int r = i >> 6, c = i & 63;
    t[r][c] = uvqk[(size_t)(k0 + r) * 2048 + c0 + c];
  }
  __syncthreads();
  for (int i = threadIdx.x; i < 64 * 64; i += 256) {
    int c = i >> 6, k = i & 63;
    Wt[(size_t)(c0 + c) * 512 + k0 + k] = f2bf(t[k][c]);
  }
}

// ---------- K2b: cast o_w (512x512, already B^T layout) -> bf16 ----------
__global__ __launch_bounds__(256) void k_cast_ow(const float* __restrict__ ow, short* __restrict__ owt) {
  int i = blockIdx.x * 256 + threadIdx.x;
  owt[i] = f2bf(ow[i]);
}

// ---------- shared GEMM core: 128x128 tile, K=512, BK=64, 4 waves ----------
// A: M x 512 row-major bf16 ; Bt: Ncols x 512 row-major bf16 (i.e. B^T)
// LDS XOR-swizzled both sides (source-swizzled global_load_lds + swizzled ds_read)
__device__ __forceinline__ void gemm_core(const short* __restrict__ A, const short* __restrict__ Bt,
                                          int t0, int c0, short* As, short* Bs, f32x4 (&acc)[4][4]) {
  int tid = threadIdx.x;
  int w = tid >> 6, lane = tid & 63, l16 = lane & 15, lq = lane >> 4;
  int wm = (w >> 1) * 64, wn = (w & 1) * 64;
  int srow = tid >> 3;                        // 0..31
  int sch = (tid & 7) ^ (srow & 7);           // swizzled source chunk
  const short* ag = A  + (size_t)(t0 + srow) * 512 + sch * 8;
  const short* bg = Bt + (size_t)(c0 + srow) * 512 + sch * 8;

  for (int k0 = 0; k0 < 512; k0 += 64) {
#pragma unroll
    for (int j = 0; j < 4; ++j) {
      gl_lds16(ag + (size_t)j * 32 * 512 + k0, (char*)As + j * 4096 + w * 1024);
      gl_lds16(bg + (size_t)j * 32 * 512 + k0, (char*)Bs + j * 4096 + w * 1024);
    }
    asm volatile("s_waitcnt vmcnt(0)" ::: "memory");
    __syncthreads();
#pragma unroll
    for (int kk = 0; kk < 2; ++kk) {
      bf16x8 af[4], bf[4];
#pragma unroll
      for (int mi = 0; mi < 4; ++mi) {
        int row = wm + mi * 16 + l16;
        af[mi] = *(const bf16x8*)&As[row * 64 + (((kk * 4 + lq) ^ (l16 & 7)) * 8)];
      }
#pragma unroll
      for (int ni = 0; ni < 4; ++ni) {
        int row = wn + ni * 16 + l16;
        bf[ni] = *(const bf16x8*)&Bs[row * 64 + (((kk * 4 + lq) ^ (l16 & 7)) * 8)];
      }
#pragma unroll
      for (int mi = 0; mi < 4; ++mi)
#pragma unroll
        for (int ni = 0; ni < 4; ++ni)
          acc[mi][ni] = mfma16(af[mi], bf[ni], acc[mi][ni]);
    }
    __syncthreads();
  }
}

// ---------- K3: proj = silu(xn @ Wt^T); v-range written transposed to Vt[b,h,d,n] ----------
__global__ __launch_bounds__(256) void k_gemm1(const short* __restrict__ A, const short* __restrict__ Bt,
                                               short* __restrict__ proj, short* __restrict__ Vt) {
  __shared__ short As[128 * 64], Bs[128 * 64];
  int c0 = blockIdx.x * 128, t0 = blockIdx.y * 128;
  f32x4 acc[4][4] = {};
  gemm_core(A, Bt, t0, c0, As, Bs, acc);
  int tid = threadIdx.x, w = tid >> 6, lane = tid & 63, l16 = lane & 15, lq = lane >> 4;
  int wm = (w >> 1) * 64, wn = (w & 1) * 64;
  bool isv = (c0 >= 512 && c0 < 1024);
#pragma unroll
  for (int mi = 0; mi < 4; ++mi)
#pragma unroll
    for (int ni = 0; ni < 4; ++ni) {
      int c = c0 + wn + ni * 16 + l16;
      int trow = t0 + wm + mi * 16 + lq * 4;
      if (isv) {
        int hh = (c - 512) >> 6, d = (c - 512) & 63;
        int bb = trow >> 11, nn = trow & 2047;
        short4v pv;
#pragma unroll
        for (int i = 0; i < 4; ++i) pv[i] = f2bf(siluf(acc[mi][ni][i]));
        *(short4v*)&Vt[((size_t)(bb * 8 + hh) * 64 + d) * 2048 + nn] = pv;
      } else {
#pragma unroll
        for (int i = 0; i < 4; ++i)
          proj[(size_t)(trow + i) * 2048 + c] = f2bf(siluf(acc[mi][ni][i]));
      }
    }
}

// ---------- K4: fused attention ----------
// attn[b,n,h*64+d] = sum_m silu(q.k + rpb[h,n,m]) * mask[b,n,m] * v[m,d]
// grid 1024 blocks; chunked-XCD order (qt,h,b); BQ=128 (32 rows/wave), BKV=128
__global__ __launch_bounds__(256) void k_attn(const short* __restrict__ proj,
                                              const short* __restrict__ Vt,
                                              const float* __restrict__ rpb,
                                              const float* __restrict__ maskp,
                                              float* __restrict__ attn) {
  __shared__ short Ks[128 * 64];
  __shared__ short Vs[64 * 128];
  __shared__ short Ps[4][32 * 128];

  int p = blockIdx.x;
  int L = (p & 7) * 128 + (p >> 3);   // chunked: 128 consecutive logical ids per XCD
  int qt = L >> 6;
  int h  = (L >> 3) & 7;
  int b  = L & 7;
  int n0 = qt * 128;

  int tid = threadIdx.x;
  int w = tid >> 6, lane = tid & 63, l16 = lane & 15, lq = lane >> 4;

  // Q fragments held in registers for whole block
  bf16x8 qf[2][2];
#pragma unroll
  for (int mi = 0; mi < 2; ++mi)
#pragma unroll
    for (int kk = 0; kk < 2; ++kk) {
      int n = n0 + w * 32 + mi * 16 + l16;
      qf[mi][kk] = *(const bf16x8*)&proj[(size_t)(b * 2048 + n) * 2048 + 1024 + h * 64 + kk * 32 + lq * 8];
    }

  int krow = tid >> 3;
  int kcs  = (tid & 7) ^ (krow & 7);
  const short* kg = proj + (size_t)(b * 2048) * 2048 + 1536 + h * 64 + kcs * 8;
  int vrow = tid >> 4;
  int vcs  = (tid & 15) ^ (vrow & 7);
  const short* vg = Vt + (size_t)(b * 8 + h) * 64 * 2048 + vcs * 8;

  const float* rpb_bh = rpb + (size_t)h * 2048 * 2048;
  const float* mask_b = maskp + (size_t)b * 2048 * 2048;

  f32x4 acc_o[2][4] = {};

  for (int kv0 = 0; kv0 < 2048; kv0 += 128) {
#pragma unroll
    for (int j = 0; j < 4; ++j)
      gl_lds16(kg + (size_t)(kv0 + j * 32 + krow) * 2048, (char*)Ks + j * 4096 + w * 1024);
#pragma unroll
    for (int j = 0; j < 4; ++j)
      gl_lds16(vg + (size_t)(j * 16 + vrow) * 2048 + kv0, (char*)Vs + j * 4096 + w * 1024);
    asm volatile("s_waitcnt vmcnt(0)" ::: "memory");
    __syncthreads();

    f32x4 s[2][8];
#pragma unroll
    for (int mi = 0; mi < 2; ++mi)
#pragma unroll
      for (int ni = 0; ni < 8; ++ni) s[mi][ni] = (f32x4){0.f, 0.f, 0.f, 0.f};

#pragma unroll
    for (int kk = 0; kk < 2; ++kk) {
      bf16x8 kf[8];
#pragma unroll
      for (int ni = 0; ni < 8; ++ni) {
        int row = ni * 16 + l16;
        int c16 = (kk * 4 + lq) ^ (row & 7);
        kf[ni] = *(const bf16x8*)&Ks[row * 64 + c16 * 8];
      }
#pragma unroll
      for (int mi = 0; mi < 2; ++mi)
#pragma unroll
        for (int ni = 0; ni < 8; ++ni)
          s[mi][ni] = mfma16(qf[mi][kk], kf[ni], s[mi][ni]);
    }

    // epilogue: +rpb, silu, *mask, -> Ps (bf16, XOR-swizzled rows)
#pragma unroll
    for (int mi = 0; mi < 2; ++mi)
#pragma unroll
      for (int i = 0; i < 4; ++i) {
        int row = mi * 16 + lq * 4 + i;         // q-local 0..31
        int n = n0 + w * 32 + row;
        const float* rr = rpb_bh + (size_t)n * 2048 + kv0 + l16;
        const float* mr = mask_b + (size_t)n * 2048 + kv0 + l16;
#pragma unroll
        for (int ni = 0; ni < 8; ++ni) {
          float xv = s[mi][ni][i] + rr[ni * 16];
          float val = xv * __builtin_amdgcn_rcpf(1.0f + __expf(-xv)) * mr[ni * 16];
          Ps[w][row * 128 + ((ni * 16 + l16) ^ ((row & 7) << 3))] = f2bf(val);
        }
      }

    // PV: O += P @ V
#pragma unroll
    for (int ks = 0; ks < 4; ++ks) {
      bf16x8 pf[2], vf[4];
#pragma unroll
      for (int pmi = 0; pmi < 2; ++pmi) {
        int row = pmi * 16 + l16;
        pf[pmi] = *(const bf16x8*)&Ps[w][row * 128 + ((ks * 32 + lq * 8) ^ ((row & 7) << 3))];
      }
#pragma unroll
      for (int ni = 0; ni < 4; ++ni) {
        int row = ni * 16 + l16;                // d row of Vt tile
        int c16 = (ks * 4 + lq) ^ (row & 7);
        vf[ni] = *(const bf16x8*)&Vs[row * 128 + c16 * 8];
      }
#pragma unroll
      for (int pmi = 0; pmi < 2; ++pmi)
#pragma unroll
        for (int ni = 0; ni < 4; ++ni)
          acc_o[pmi][ni] = mfma16(pf[pmi], vf[ni], acc_o[pmi][ni]);
    }
    __syncthreads();
  }

#pragma unroll
  for (int pmi = 0; pmi < 2; ++pmi)
#pragma unroll
    for (int ni = 0; ni < 4; ++ni)
#pragma unroll
      for (int i = 0; i < 4; ++i) {
        int n = n0 + w * 32 + pmi * 16 + lq * 4 + i;
        attn[(size_t)(b * 2048 + n) * 512 + h * 64 + ni * 16 + l16] = acc_o[pmi][ni][i];
      }
}

// ---------- K5: gated = u * LayerNorm(attn) -> bf16 ----------
__global__ __launch_bounds__(256) void k_gate(const float* __restrict__ attn, const short* __restrict__ proj,
                                              short* __restrict__ gated) {
  int row = blockIdx.x * 4 + (threadIdx.x >> 6);
  int lane = threadIdx.x & 63;
  const float4* ar = (const float4*)(attn + (size_t)row * 512);
  float4 a = ar[lane * 2], b = ar[lane * 2 + 1];
  float s  = a.x + a.y + a.z + a.w + b.x + b.y + b.z + b.w;
  float s2 = a.x*a.x + a.y*a.y + a.z*a.z + a.w*a.w + b.x*b.x + b.y*b.y + b.z*b.z + b.w*b.w;
#pragma unroll
  for (int m = 1; m < 64; m <<= 1) { s += __shfl_xor(s, m); s2 += __shfl_xor(s2, m); }
  float mu = s * (1.f / 512.f);
  float rstd = rsqrtf(s2 * (1.f / 512.f) - mu * mu + 1e-6f);
  float v[8] = {a.x, a.y, a.z, a.w, b.x, b.y, b.z, b.w};
  short8v u = *(const short8v*)&proj[(size_t)row * 2048 + lane * 8];
  short8v g;
#pragma unroll
  for (int j = 0; j < 8; ++j) g[j] = f2bf(bf2f(u[j]) * ((v[j] - mu) * rstd));
  *(short8v*)&gated[(size_t)row * 512 + lane * 8] = g;
}

// ---------- K6: out = gated @ owt^T + o_b + x ----------
__global__ __launch_bounds__(256) void k_gemm2(const short* __restrict__ A, const short* __restrict__ Bt,
                                               const float* __restrict__ ob, const float* __restrict__ x,
                                               float* __restrict__ out) {
  __shared__ short As[128 * 64], Bs[128 * 64];
  int c0 = blockIdx.x * 128, t0 = blockIdx.y * 128;
  f32x4 acc[4][4] = {};
  gemm_core(A, Bt, t0, c0, As, Bs, acc);
  int tid = threadIdx.x, w = tid >> 6, lane = tid & 63, l16 = lane & 15, lq = lane >> 4;
  int wm = (w >> 1) * 64, wn = (w & 1) * 64;
#pragma unroll
  for (int mi = 0; mi < 4; ++mi)
#pragma unroll
    for (int ni = 0; ni < 4; ++ni) {
      int e = c0 + wn + ni * 16 + l16;
      float bias = ob[e];
#pragma unroll
      for (int i = 0; i < 4; ++i) {
        int t = t0 + wm + mi * 16 + lq * 4 + i;
        out[(size_t)t * 512 + e] = acc[mi][ni][i] + bias + x[(size_t)t * 512 + e];
      }
    }
}

// ---------- launch ----------
extern "C" void kernel_launch(void* const* d_in, const int* in_sizes, int n_in,
                              void* d_out, int out_size, void* d_ws, size_t ws_size,
                              hipStream_t stream) {
  const float* x    = (const float*)d_in[0];
  const float* rpb  = (const float*)d_in[1];
  const float* mask = (const float*)d_in[2];
  const float* uvqk = (const float*)d_in[3];
  const float* o_w  = (const float*)d_in[4];
  const float* o_b  = (const float*)d_in[5];
  float* out = (float*)d_out;

  char* p = (char*)d_ws;
  short* xn   = (short*)p; p += 16384ull * 512 * 2;      // 16 MB (reused as `gated`)
  short* Wt   = (short*)p; p += 2048ull * 512 * 2;       // 2 MB
  short* owt  = (short*)p; p += 512ull * 512 * 2;        // 0.5 MB
  short* proj = (short*)p; p += 16384ull * 2048 * 2;     // 64 MB
  short* Vt   = (short*)p; p += 8ull * 8 * 64 * 2048 * 2;// 16 MB
  float* attn = (float*)p; p += 16384ull * 512 * 4;      // 32 MB
  short* gated = xn;                                     // xn dead after GEMM1

  k_ln    <<<4096, 256, 0, stream>>>(x, xn);
  k_prep_w<<<dim3(8, 32), 256, 0, stream>>>(uvqk, Wt);
  k_cast_ow<<<1024, 256, 0, stream>>>(o_w, owt);
  k_gemm1 <<<dim3(16, 128), 256, 0, stream>>>(xn, Wt, proj, Vt);
  k_attn  <<<1024, 256, 0, stream>>>(proj, Vt, rpb, mask, attn);
  k_gate  <<<4096, 256, 0, stream>>>(attn, proj, gated);
  k_gemm2 <<<dim3(4, 128), 256, 0, stream>>>(gated, owt, o_b, x, out);
}

// Round 2
// 364.892 us; speedup vs baseline: 5.2221x; 5.2221x over previous
//
#include <hip/hip_runtime.h>
#include <stdint.h>

// ---------- types ----------
typedef short bf16x8   __attribute__((ext_vector_type(8)));
typedef short short4v  __attribute__((ext_vector_type(4)));
typedef short short8v  __attribute__((ext_vector_type(8)));
typedef float f32x4    __attribute__((ext_vector_type(4)));

typedef __attribute__((address_space(3))) uint32_t lds_u32;
typedef const __attribute__((address_space(1))) uint32_t glob_u32;

__device__ __forceinline__ void gl_lds16(const void* g, void* l) {
  __builtin_amdgcn_global_load_lds((glob_u32*)g, (lds_u32*)l, 16, 0, 0);
}

__device__ __forceinline__ float bf2f(short u) {
  union { float f; uint32_t i; } v; v.i = ((uint32_t)(uint16_t)u) << 16; return v.f;
}
__device__ __forceinline__ short f2bf(float f) {
  union { float f; uint32_t i; } v; v.f = f;
  uint32_t r = v.i + 0x7FFFu + ((v.i >> 16) & 1u);
  return (short)(r >> 16);
}
__device__ __forceinline__ float siluf(float x) {
  return x * __builtin_amdgcn_rcpf(1.0f + __expf(-x));
}
__device__ __forceinline__ f32x4 mfma16(bf16x8 a, bf16x8 b, f32x4 c) {
  return __builtin_amdgcn_mfma_f32_16x16x32_bf16(a, b, c, 0, 0, 0);
}

// ---------- K1: LayerNorm(x) -> bf16 ----------
__global__ __launch_bounds__(256) void k_ln(const float* __restrict__ x, short* __restrict__ xn) {
  int row = blockIdx.x * 4 + (threadIdx.x >> 6);
  int lane = threadIdx.x & 63;
  const float4* xr = (const float4*)(x + (size_t)row * 512);
  float4 a = xr[lane * 2], b = xr[lane * 2 + 1];
  float s  = a.x + a.y + a.z + a.w + b.x + b.y + b.z + b.w;
  float s2 = a.x*a.x + a.y*a.y + a.z*a.z + a.w*a.w + b.x*b.x + b.y*b.y + b.z*b.z + b.w*b.w;
#pragma unroll
  for (int m = 1; m < 64; m <<= 1) { s += __shfl_xor(s, m); s2 += __shfl_xor(s2, m); }
  float mu = s * (1.f / 512.f);
  float rstd = rsqrtf(s2 * (1.f / 512.f) - mu * mu + 1e-6f);
  float v[8] = {a.x, a.y, a.z, a.w, b.x, b.y, b.z, b.w};
  short8v o;
#pragma unroll
  for (int j = 0; j < 8; ++j) o[j] = f2bf((v[j] - mu) * rstd);
  *(short8v*)&xn[(size_t)row * 512 + lane * 8] = o;
}

// ---------- K2: transpose+cast uvqk (512x2048) -> Wt (2048x512) bf16 ----------
__global__ __launch_bounds__(256) void k_prep_w(const float* __restrict__ uvqk, short* __restrict__ Wt) {
  __shared__ float t[64][65];
  int k0 = blockIdx.x * 64;
  int c0 = blockIdx.y * 64;
  for (int i = threadIdx.x; i < 64 * 64; i += 256) {
    int r = i >> 6, c = i & 63;
    t[r][c] = uvqk[(size_t)(k0 + r) * 2048 + c0 + c];
  }
  __syncthreads();
  for (int i = threadIdx.x; i < 64 * 64; i += 256) {
    int c = i >> 6, k = i & 63;
    Wt[(size_t)(c0 + c) * 512 + k0 + k] = f2bf(t[k][c]);
  }
}

// ---------- K2b: cast o_w ----------
__global__ __launch_bounds__(256) void k_cast_ow(const float* __restrict__ ow, short* __restrict__ owt) {
  int i = blockIdx.x * 256 + threadIdx.x;
  owt[i] = f2bf(ow[i]);
}

// ---------- shared GEMM core: 128x128 tile, K=512, BK=64, 4 waves ----------
__device__ __forceinline__ void gemm_core(const short* __restrict__ A, const short* __restrict__ Bt,
                                          int t0, int c0, short* As, short* Bs, f32x4 (&acc)[4][4]) {
  int tid = threadIdx.x;
  int w = tid >> 6, lane = tid & 63, l16 = lane & 15, lq = lane >> 4;
  int wm = (w >> 1) * 64, wn = (w & 1) * 64;
  int srow = tid >> 3;
  int sch = (tid & 7) ^ (srow & 7);
  const short* ag = A  + (size_t)(t0 + srow) * 512 + sch * 8;
  const short* bg = Bt + (size_t)(c0 + srow) * 512 + sch * 8;

  for (int k0 = 0; k0 < 512; k0 += 64) {
#pragma unroll
    for (int j = 0; j < 4; ++j) {
      gl_lds16(ag + (size_t)j * 32 * 512 + k0, (char*)As + j * 4096 + w * 1024);
      gl_lds16(bg + (size_t)j * 32 * 512 + k0, (char*)Bs + j * 4096 + w * 1024);
    }
    asm volatile("s_waitcnt vmcnt(0)" ::: "memory");
    __syncthreads();
#pragma unroll
    for (int kk = 0; kk < 2; ++kk) {
      bf16x8 af[4], bf[4];
#pragma unroll
      for (int mi = 0; mi < 4; ++mi) {
        int row = wm + mi * 16 + l16;
        af[mi] = *(const bf16x8*)&As[row * 64 + (((kk * 4 + lq) ^ (l16 & 7)) * 8)];
      }
#pragma unroll
      for (int ni = 0; ni < 4; ++ni) {
        int row = wn + ni * 16 + l16;
        bf[ni] = *(const bf16x8*)&Bs[row * 64 + (((kk * 4 + lq) ^ (l16 & 7)) * 8)];
      }
#pragma unroll
      for (int mi = 0; mi < 4; ++mi)
#pragma unroll
        for (int ni = 0; ni < 4; ++ni)
          acc[mi][ni] = mfma16(af[mi], bf[ni], acc[mi][ni]);
    }
    __syncthreads();
  }
}

// ---------- K3: proj = silu(xn @ Wt^T); v written transposed to Vt[b,h,d,n] ----------
__global__ __launch_bounds__(256) void k_gemm1(const short* __restrict__ A, const short* __restrict__ Bt,
                                               short* __restrict__ proj, short* __restrict__ Vt) {
  __shared__ short As[128 * 64], Bs[128 * 64];
  int c0 = blockIdx.x * 128, t0 = blockIdx.y * 128;
  f32x4 acc[4][4] = {};
  gemm_core(A, Bt, t0, c0, As, Bs, acc);
  int tid = threadIdx.x, w = tid >> 6, lane = tid & 63, l16 = lane & 15, lq = lane >> 4;
  int wm = (w >> 1) * 64, wn = (w & 1) * 64;
  bool isv = (c0 >= 512 && c0 < 1024);
#pragma unroll
  for (int mi = 0; mi < 4; ++mi)
#pragma unroll
    for (int ni = 0; ni < 4; ++ni) {
      int c = c0 + wn + ni * 16 + l16;
      int trow = t0 + wm + mi * 16 + lq * 4;
      if (isv) {
        int hh = (c - 512) >> 6, d = (c - 512) & 63;
        int bb = trow >> 11, nn = trow & 2047;
        short4v pv;
#pragma unroll
        for (int i = 0; i < 4; ++i) pv[i] = f2bf(siluf(acc[mi][ni][i]));
        *(short4v*)&Vt[((size_t)(bb * 8 + hh) * 64 + d) * 2048 + nn] = pv;
      } else {
#pragma unroll
        for (int i = 0; i < 4; ++i)
          proj[(size_t)(trow + i) * 2048 + c] = f2bf(siluf(acc[mi][ni][i]));
      }
    }
}

// ---------- K4: fused attention (restructured) ----------
// BQ=128 (32 q-rows/wave), BKV=64. Per iter:
//   [bar] gl_lds K,V + issue rpb/mask float4 loads -> vmcnt(16) [bar]
//   QK^T MFMA -> S(fp32) to padded LDS -> lgkm(0) [bar]
//   coalesced-ownership epilogue: S + rpb, silu, *mask -> Ps (bf16, swizzled) -> lgkm(0) [bar]
//   PV MFMA
__global__ __launch_bounds__(256) void k_attn(const short* __restrict__ proj,
                                              const short* __restrict__ Vt,
                                              const float* __restrict__ rpb,
                                              const float* __restrict__ maskp,
                                              float* __restrict__ attn) {
  __shared__ __align__(16) short Ks[64 * 64];    // [kv][d], c16 ^= row&7
  __shared__ __align__(16) short Vs[64 * 64];    // [d][kv], c16 ^= row&7
  __shared__ __align__(16) float Sr[128 * 68];   // padded fp32 S tile
  __shared__ __align__(16) short Ps[128 * 64];   // bf16 P tile, c16 ^= row&7

  int p = blockIdx.x;
  int L = (p & 7) * 128 + (p >> 3);   // chunked XCD swizzle (1024 % 8 == 0, bijective)
  int qt = L >> 6, h = (L >> 3) & 7, b = L & 7;
  int n0 = qt * 128;

  int tid = threadIdx.x;
  int w = tid >> 6, lane = tid & 63, l16 = lane & 15, lq = lane >> 4;

  // Q fragments in registers for whole block
  bf16x8 qf[2][2];
#pragma unroll
  for (int mi = 0; mi < 2; ++mi)
#pragma unroll
    for (int kk = 0; kk < 2; ++kk) {
      int n = n0 + w * 32 + mi * 16 + l16;
      qf[mi][kk] = *(const bf16x8*)&proj[(size_t)(b * 2048 + n) * 2048 + 1024 + h * 64 + kk * 32 + lq * 8];
    }

  // staging lane constants (row&7 == lane>>3 within each wave's 8-row group)
  int j8 = lane >> 3, c8 = lane & 7;
  int srcc = (c8 ^ j8) * 8;                     // pre-swizzled source 16B-chunk
  const short* kg = proj + (size_t)(b * 2048) * 2048 + 1536 + h * 64 + srcc;
  const short* vg = Vt + (size_t)((b * 8 + h) * 64) * 2048 + srcc;

  // epilogue ownership: element id = jj*256 + tid -> r = jj*16 + (tid>>4), c4 = tid&15
  int er = tid >> 4, ec = tid & 15;
  const float* rpb_p = rpb + (size_t)h * 4194304 + (size_t)(n0 + er) * 2048 + ec * 4;
  const float* msk_p = maskp + (size_t)b * 4194304 + (size_t)(n0 + er) * 2048 + ec * 4;

  f32x4 acc_o[2][4] = {};

  for (int kv0 = 0; kv0 < 2048; kv0 += 64) {
    __builtin_amdgcn_s_barrier();               // prev iter done reading Ks/Vs/Ps
    // stage K,V (4 gl_lds per wave)
#pragma unroll
    for (int j = 0; j < 2; ++j)
      gl_lds16(kg + (size_t)(kv0 + w * 16 + j * 8 + j8) * 2048, Ks + w * 1024 + j * 512);
#pragma unroll
    for (int j = 0; j < 2; ++j)
      gl_lds16(vg + (size_t)(w * 16 + j * 8 + j8) * 2048 + kv0, Vs + w * 1024 + j * 512);
    __builtin_amdgcn_sched_barrier(0);
    // issue rpb/mask loads early (consumed after S barrier; latency hides under QK)
    float4 rv[8], mv[8];
#pragma unroll
    for (int jj = 0; jj < 8; ++jj) {
      rv[jj] = *(const float4*)(rpb_p + (size_t)jj * 32768 + kv0);
      mv[jj] = *(const float4*)(msk_p + (size_t)jj * 32768 + kv0);
    }
    __builtin_amdgcn_sched_barrier(0);
    asm volatile("s_waitcnt vmcnt(16)" ::: "memory");   // only the 4 gl_lds
    __builtin_amdgcn_s_barrier();               // Ks/Vs valid

    // QK^T
    f32x4 s[2][4] = {};
#pragma unroll
    for (int kk = 0; kk < 2; ++kk) {
      bf16x8 kf[4];
#pragma unroll
      for (int ni = 0; ni < 4; ++ni)
        kf[ni] = *(const bf16x8*)&Ks[(ni * 16 + l16) * 64 + (((kk * 4 + lq) ^ (l16 & 7)) * 8)];
#pragma unroll
      for (int mi = 0; mi < 2; ++mi)
#pragma unroll
        for (int ni = 0; ni < 4; ++ni)
          s[mi][ni] = mfma16(qf[mi][kk], kf[ni], s[mi][ni]);
    }
    // S -> LDS (padded rows: 68 floats = 17x16B, keeps b128 alignment)
#pragma unroll
    for (int mi = 0; mi < 2; ++mi)
#pragma unroll
      for (int ni = 0; ni < 4; ++ni)
#pragma unroll
        for (int i = 0; i < 4; ++i)
          Sr[(w * 32 + mi * 16 + lq * 4 + i) * 68 + ni * 16 + l16] = s[mi][ni][i];
    asm volatile("s_waitcnt lgkmcnt(0)" ::: "memory");
    __builtin_amdgcn_s_barrier();               // Sr complete

    // epilogue: coalesced-ownership (4 consecutive cols/thread)
#pragma unroll
    for (int jj = 0; jj < 8; ++jj) {
      int r = jj * 16 + er;
      f32x4 sv = *(const f32x4*)&Sr[r * 68 + ec * 4];
      float xr[4] = {rv[jj].x, rv[jj].y, rv[jj].z, rv[jj].w};
      float xm[4] = {mv[jj].x, mv[jj].y, mv[jj].z, mv[jj].w};
      short4v pk;
#pragma unroll
      for (int e = 0; e < 4; ++e) {
        float xx = sv[e] + xr[e];
        pk[e] = f2bf(siluf(xx) * xm[e]);
      }
      *(short4v*)((char*)Ps + r * 128 + (((ec >> 1) ^ (r & 7)) * 16) + (ec & 1) * 8) = pk;
    }
    asm volatile("s_waitcnt lgkmcnt(0)" ::: "memory");
    __builtin_amdgcn_s_barrier();               // Ps complete

    // PV
#pragma unroll
    for (int ks = 0; ks < 2; ++ks) {
      bf16x8 pf[2], vf[4];
#pragma unroll
      for (int mi = 0; mi < 2; ++mi) {
        int rp = w * 32 + mi * 16 + l16;
        pf[mi] = *(const bf16x8*)((const char*)Ps + rp * 128 + (((ks * 4 + lq) ^ (rp & 7)) * 16));
      }
#pragma unroll
      for (int ni = 0; ni < 4; ++ni)
        vf[ni] = *(const bf16x8*)&Vs[(ni * 16 + l16) * 64 + (((ks * 4 + lq) ^ (l16 & 7)) * 8)];
#pragma unroll
      for (int mi = 0; mi < 2; ++mi)
#pragma unroll
        for (int ni = 0; ni < 4; ++ni)
          acc_o[mi][ni] = mfma16(pf[mi], vf[ni], acc_o[mi][ni]);
    }
  }

#pragma unroll
  for (int mi = 0; mi < 2; ++mi)
#pragma unroll
    for (int ni = 0; ni < 4; ++ni)
#pragma unroll
      for (int i = 0; i < 4; ++i) {
        int n = n0 + w * 32 + mi * 16 + lq * 4 + i;
        attn[(size_t)(b * 2048 + n) * 512 + h * 64 + ni * 16 + l16] = acc_o[mi][ni][i];
      }
}

// ---------- K5: gated = u * LayerNorm(attn) -> bf16 ----------
__global__ __launch_bounds__(256) void k_gate(const float* __restrict__ attn, const short* __restrict__ proj,
                                              short* __restrict__ gated) {
  int row = blockIdx.x * 4 + (threadIdx.x >> 6);
  int lane = threadIdx.x & 63;
  const float4* ar = (const float4*)(attn + (size_t)row * 512);
  float4 a = ar[lane * 2], b = ar[lane * 2 + 1];
  float s  = a.x + a.y + a.z + a.w + b.x + b.y + b.z + b.w;
  float s2 = a.x*a.x + a.y*a.y + a.z*a.z + a.w*a.w + b.x*b.x + b.y*b.y + b.z*b.z + b.w*b.w;
#pragma unroll
  for (int m = 1; m < 64; m <<= 1) { s += __shfl_xor(s, m); s2 += __shfl_xor(s2, m); }
  float mu = s * (1.f / 512.f);
  float rstd = rsqrtf(s2 * (1.f / 512.f) - mu * mu + 1e-6f);
  float v[8] = {a.x, a.y, a.z, a.w, b.x, b.y, b.z, b.w};
  short8v u = *(const short8v*)&proj[(size_t)row * 2048 + lane * 8];
  short8v g;
#pragma unroll
  for (int j = 0; j < 8; ++j) g[j] = f2bf(bf2f(u[j]) * ((v[j] - mu) * rstd));
  *(short8v*)&gated[(size_t)row * 512 + lane * 8] = g;
}

// ---------- K6: out = gated @ owt^T + o_b + x ----------
__global__ __launch_bounds__(256) void k_gemm2(const short* __restrict__ A, const short* __restrict__ Bt,
                                               const float* __restrict__ ob, const float* __restrict__ x,
                                               float* __restrict__ out) {
  __shared__ short As[128 * 64], Bs[128 * 64];
  int c0 = blockIdx.x * 128, t0 = blockIdx.y * 128;
  f32x4 acc[4][4] = {};
  gemm_core(A, Bt, t0, c0, As, Bs, acc);
  int tid = threadIdx.x, w = tid >> 6, lane = tid & 63, l16 = lane & 15, lq = lane >> 4;
  int wm = (w >> 1) * 64, wn = (w & 1) * 64;
#pragma unroll
  for (int mi = 0; mi < 4; ++mi)
#pragma unroll
    for (int ni = 0; ni < 4; ++ni) {
      int e = c0 + wn + ni * 16 + l16;
      float bias = ob[e];
#pragma unroll
      for (int i = 0; i < 4; ++i) {
        int t = t0 + wm + mi * 16 + lq * 4 + i;
        out[(size_t)t * 512 + e] = acc[mi][ni][i] + bias + x[(size_t)t * 512 + e];
      }
    }
}

// ---------- launch ----------
extern "C" void kernel_launch(void* const* d_in, const int* in_sizes, int n_in,
                              void* d_out, int out_size, void* d_ws, size_t ws_size,
                              hipStream_t stream) {
  const float* x    = (const float*)d_in[0];
  const float* rpb  = (const float*)d_in[1];
  const float* mask = (const float*)d_in[2];
  const float* uvqk = (const float*)d_in[3];
  const float* o_w  = (const float*)d_in[4];
  const float* o_b  = (const float*)d_in[5];
  float* out = (float*)d_out;

  char* p = (char*)d_ws;
  short* xn   = (short*)p; p += 16384ull * 512 * 2;
  short* Wt   = (short*)p; p += 2048ull * 512 * 2;
  short* owt  = (short*)p; p += 512ull * 512 * 2;
  short* proj = (short*)p; p += 16384ull * 2048 * 2;
  short* Vt   = (short*)p; p += 8ull * 8 * 64 * 2048 * 2;
  float* attn = (float*)p; p += 16384ull * 512 * 4;
  short* gated = xn;

  k_ln    <<<4096, 256, 0, stream>>>(x, xn);
  k_prep_w<<<dim3(8, 32), 256, 0, stream>>>(uvqk, Wt);
  k_cast_ow<<<1024, 256, 0, stream>>>(o_w, owt);
  k_gemm1 <<<dim3(16, 128), 256, 0, stream>>>(xn, Wt, proj, Vt);
  k_attn  <<<1024, 256, 0, stream>>>(proj, Vt, rpb, mask, attn);
  k_gate  <<<4096, 256, 0, stream>>>(attn, proj, gated);
  k_gemm2 <<<dim3(4, 128), 256, 0, stream>>>(gated, owt, o_b, x, out);
}